// Round 14
// baseline (41.324 us; speedup 1.0000x reference)
//
#include <hip/hip_runtime.h>
#include <math.h>

// Problem constants (B=4, S=2048, D=1024, C=10)
constexpr int D_DIM = 1024;
constexpr int C_DIM = 10;

constexpr float CLAMP_V  = 1.0e6f;
constexpr float LOG2E    = 1.4426950408889634f;
constexpr float LN2      = 0.6931471805599453f;
constexpr float INV_2PI  = 0.15915494309189535f;

using bf16x8 = __attribute__((ext_vector_type(8))) short;   // MFMA A/B frag
using f32x4  = __attribute__((ext_vector_type(4))) float;   // MFMA C/D frag

// float2 helpers -> coax v_pk_{fma,mul,add}_f32
__device__ __forceinline__ float2 pmul(float2 a, float2 b) {
    return make_float2(a.x * b.x, a.y * b.y);
}
__device__ __forceinline__ float2 pfma(float2 a, float2 b, float2 c) {
    return make_float2(fmaf(a.x, b.x, c.x), fmaf(a.y, b.y, c.y));
}
__device__ __forceinline__ float2 padd(float2 a, float2 b) {
    return make_float2(a.x + b.x, a.y + b.y);
}
__device__ __forceinline__ float2 bc(float s) { return make_float2(s, s); }

// wave-uniform value -> SGPR
__device__ __forceinline__ float rfl(float x) {
    return __int_as_float(__builtin_amdgcn_readfirstlane(__float_as_int(x)));
}

// ---- DPP wave64 sum -> SGPR (full-rate VALU, no LDS pipe) ----
template <int CTRL>
__device__ __forceinline__ float dpp_add(float v) {
    const int s = __builtin_amdgcn_update_dpp(
        0, __float_as_int(v), CTRL, 0xf, 0xf, false);
    return v + __int_as_float(s);
}
__device__ __forceinline__ float wave_sum_sgpr(float v) {
    v = dpp_add<0x111>(v);   // row_shr:1
    v = dpp_add<0x112>(v);   // row_shr:2
    v = dpp_add<0x114>(v);   // row_shr:4
    v = dpp_add<0x118>(v);   // row_shr:8
    v = dpp_add<0x142>(v);   // row_bcast:15
    v = dpp_add<0x143>(v);   // row_bcast:31 -> lane 63 = total
    return __int_as_float(__builtin_amdgcn_readlane(__float_as_int(v), 63));
}

// ======== kernel A: logits = x @ gate_w^T + gate_b  (MFMA, bf16 3-term) ====
// One wave per 16-token tile. A[m][k]: lane l&15 = m, k = (l>>4)*8+j.
// B[k][n]:  lane l&15 = n, k = (l>>4)*8+j.  D: row=(l>>4)*4+r, col=l&15.
__global__ __launch_bounds__(64)
void logits_kernel(const float* __restrict__ x,
                   const float* __restrict__ gate_w,
                   const float* __restrict__ gate_b,
                   float* __restrict__ logits,     // (tokens, 16)
                   int tokens)
{
    const int l    = threadIdx.x;
    const int col  = l & 15;
    const int kgrp = l >> 4;

    const int tile = blockIdx.x;
    const int arow = min(tile * 16 + col, tokens - 1);     // token (A row)
    const int wrow = (col < C_DIM) ? col : 0;              // clamped B row
    const float bm = (col < C_DIM) ? 1.0f : 0.0f;          // zero pad cols

    const float* px = x + (size_t)arow * D_DIM + (kgrp << 3);
    const float* pw = gate_w + (size_t)wrow * D_DIM + (kgrp << 3);

    f32x4 acc0 = {0.f, 0.f, 0.f, 0.f};
    f32x4 acc1 = {0.f, 0.f, 0.f, 0.f};
    f32x4 acc2 = {0.f, 0.f, 0.f, 0.f};

    for (int ks = 0; ks < D_DIM / 32; ++ks) {
        const float4 a0 = *reinterpret_cast<const float4*>(px + ks * 32);
        const float4 a1 = *reinterpret_cast<const float4*>(px + ks * 32 + 4);
        const float4 b0 = *reinterpret_cast<const float4*>(pw + ks * 32);
        const float4 b1 = *reinterpret_cast<const float4*>(pw + ks * 32 + 4);

        const float af[8] = {a0.x, a0.y, a0.z, a0.w, a1.x, a1.y, a1.z, a1.w};
        const float bf[8] = {b0.x * bm, b0.y * bm, b0.z * bm, b0.w * bm,
                             b1.x * bm, b1.y * bm, b1.z * bm, b1.w * bm};
        bf16x8 ah, al, bh, bl;
#pragma unroll
        for (int j = 0; j < 8; ++j) {
            const unsigned ua = __float_as_uint(af[j]);
            ah[j] = (short)(ua >> 16);                       // truncated hi
            al[j] = (short)(__float_as_uint(
                        af[j] - __uint_as_float(ua & 0xffff0000u)) >> 16);
            const unsigned ub = __float_as_uint(bf[j]);
            bh[j] = (short)(ub >> 16);
            bl[j] = (short)(__float_as_uint(
                        bf[j] - __uint_as_float(ub & 0xffff0000u)) >> 16);
        }
        acc0 = __builtin_amdgcn_mfma_f32_16x16x32_bf16(ah, bh, acc0, 0, 0, 0);
        acc1 = __builtin_amdgcn_mfma_f32_16x16x32_bf16(ah, bl, acc1, 0, 0, 0);
        acc2 = __builtin_amdgcn_mfma_f32_16x16x32_bf16(al, bh, acc2, 0, 0, 0);
    }

    const float bias = (col < C_DIM) ? gate_b[col] : 0.0f;
#pragma unroll
    for (int r = 0; r < 4; ++r) {
        const int trow = tile * 16 + (l >> 4) * 4 + r;
        if (trow < tokens)
            logits[trow * 16 + col] = (acc0[r] + acc1[r]) + acc2[r] + bias;
    }
}

// ======== kernel B: LN + softmax + candidates + joint-LN + write ===========
// No LDS, no barriers, wave-private token. Target VGPR <= 64.
__global__ __launch_bounds__(256)
void fused_kernel(const float* __restrict__ x,
                  const float* __restrict__ ln_gamma,
                  const float* __restrict__ ln_beta,
                  const float* __restrict__ log_in_scale,
                  const float* __restrict__ log_out_scale,
                  const float* __restrict__ logits,     // (tokens, 16)
                  float* __restrict__ out_weighted,     // (tokens, D)
                  float* __restrict__ out_gate,         // (tokens, C)
                  int tokens)
{
    const int lane = threadIdx.x & 63;
    int token = blockIdx.x * 4 + (threadIdx.x >> 6);
    token = min(token, tokens - 1);

    // this wave's 16 x-elements: d = k*256 + lane*4 (coalesced f4)
    const float* xrow = x + (size_t)token * D_DIM + (lane << 2);
    float4 xv[4];
#pragma unroll
    for (int k = 0; k < 4; ++k)
        xv[k] = *reinterpret_cast<const float4*>(xrow + k * 256);

    // LN partials -> DPP reduce -> SGPR
    float2 s = bc(0.0f), q = bc(0.0f);
#pragma unroll
    for (int k = 0; k < 4; ++k) {
        const float2 lo = make_float2(xv[k].x, xv[k].y);
        const float2 hi = make_float2(xv[k].z, xv[k].w);
        s = padd(s, padd(lo, hi));
        q = pfma(lo, lo, q);
        q = pfma(hi, hi, q);
    }
    const float r0 = wave_sum_sgpr(s.x + s.y);
    const float r1 = wave_sum_sgpr(q.x + q.y);

    const float mu   = r0 * (1.0f / D_DIM);
    const float var  = r1 * (1.0f / D_DIM) - mu * mu;
    const float rstd = rfl(rsqrtf(var + 1e-5f));

    // gate softmax from precomputed logits (wave-uniform scalar loads)
    const float* st = logits + token * 16;
    float w[C_DIM];
    float gmax = -3.4e38f;
#pragma unroll
    for (int c = 0; c < C_DIM; ++c) {
        w[c] = st[c];
        gmax = fmaxf(gmax, w[c]);
    }
    float esum = 0.0f;
#pragma unroll
    for (int c = 0; c < C_DIM; ++c) {
        w[c] = __builtin_amdgcn_exp2f((w[c] - gmax) * LOG2E);
        esum += w[c];
    }
    const float rsum = __builtin_amdgcn_rcpf(esum);
#pragma unroll
    for (int c = 0; c < C_DIM; ++c) w[c] = rfl(w[c] * rsum);

    if (lane < C_DIM) out_gate[token * C_DIM + lane] = w[lane];

    // scales (grid-uniform; one-time; SGPR via rfl)
    float in_s[C_DIM], out_s[C_DIM];
#pragma unroll
    for (int c = 0; c < C_DIM; ++c) {
        in_s[c]  = __builtin_amdgcn_exp2f(log_in_scale[c]  * LOG2E);
        out_s[c] = __builtin_amdgcn_exp2f(log_out_scale[c] * LOG2E);
    }
    // derived constants; |xn| <= ~42 => only exp's output clamp can fire
    const float a0 = rfl(out_s[0] * in_s[0]);
    const float a1 = rfl(out_s[1] * in_s[1] * in_s[1]);
    const float k2 = rfl(in_s[2]),           o2 = rfl(out_s[2]);
    const float k3 = rfl(in_s[3] * INV_2PI), o3 = rfl(out_s[3]);
    const float k4 = rfl(in_s[4] * LOG2E),   o4 = rfl(out_s[4]);
    const float v5 = rfl(fminf(out_s[5], CLAMP_V));
    const float a6 = rfl(out_s[6] * in_s[6] * in_s[6] * in_s[6]);
    const float k7 = rfl(in_s[7]),           o7 = rfl(out_s[7] * LN2);
    const float k8 = rfl(in_s[8]),           o8 = rfl(out_s[8]);
    const float k9 = rfl(2.0f * in_s[9] * LOG2E);
    const float o9 = rfl(out_s[9]),          m9 = rfl(-2.0f * out_s[9]);

    // normalized x (xv dies here)
    float2 xn[8];
#pragma unroll
    for (int k = 0; k < 4; ++k) {
        const float4 gv = *reinterpret_cast<const float4*>(ln_gamma + k * 256 + (lane << 2));
        const float4 bv = *reinterpret_cast<const float4*>(ln_beta  + k * 256 + (lane << 2));
        const float2 zlo = pmul(padd(make_float2(xv[k].x, xv[k].y), bc(-mu)), bc(rstd));
        const float2 zhi = pmul(padd(make_float2(xv[k].z, xv[k].w), bc(-mu)), bc(rstd));
        xn[2 * k]     = pfma(zlo, make_float2(gv.x, gv.y), make_float2(bv.x, bv.y));
        xn[2 * k + 1] = pfma(zhi, make_float2(gv.z, gv.w), make_float2(bv.z, bv.w));
    }

    // candidate pass: joint-LN stats + gated accumulation (packed f32, SGPR
    // constants). weighted = (sum_c w_c*cand_c - mu2)*rsig; post-LN clip/nan
    // dead; sum w = 1; c5 hoisted. acc overwrites xn in place.
    const float accbase = rfl(w[5] * v5);
    float2 S1 = bc(0.0f), S2 = bc(0.0f);

#pragma unroll
    for (int p = 0; p < 8; ++p) {
        const float2 xj = xn[p];
        const float2 ax = make_float2(fabsf(xj.x), fabsf(xj.y));
        const float2 x2 = pmul(xj, xj);

        const float2 v0 = pmul(bc(a0), xj);
        const float2 v1 = pmul(bc(a1), x2);

        float2 u2 = pmul(bc(k2), xj);
        u2 = padd(u2, make_float2(-rintf(u2.x), -rintf(u2.y)));
        const float2 v2 = pmul(bc(o2),
            make_float2(__builtin_amdgcn_cosf(u2.x), __builtin_amdgcn_cosf(u2.y)));

        float2 u3 = pmul(bc(k3), xj);
        u3 = padd(u3, make_float2(-rintf(u3.x), -rintf(u3.y)));
        const float2 v3 = pmul(bc(o3),
            make_float2(__builtin_amdgcn_sinf(u3.x), __builtin_amdgcn_sinf(u3.y)));

        const float2 u4 = pmul(bc(k4), xj);
        float2 v4 = pmul(bc(o4),
            make_float2(__builtin_amdgcn_exp2f(u4.x), __builtin_amdgcn_exp2f(u4.y)));
        v4 = make_float2(fminf(v4.x, CLAMP_V), fminf(v4.y, CLAMP_V));

        const float2 v6 = pmul(bc(a6), pmul(x2, xj));

        const float2 u7 = pfma(bc(k7), ax, bc(1.0f));
        const float2 v7 = pmul(bc(o7),
            make_float2(__builtin_amdgcn_logf(u7.x), __builtin_amdgcn_logf(u7.y)));

        const float2 u8 = pmul(bc(k8), ax);
        const float2 v8 = pmul(bc(o8),
            make_float2(__builtin_amdgcn_sqrtf(u8.x), __builtin_amdgcn_sqrtf(u8.y)));

        const float2 u9 = pmul(bc(k9), xj);
        const float2 e9 = padd(
            make_float2(__builtin_amdgcn_exp2f(u9.x), __builtin_amdgcn_exp2f(u9.y)),
            bc(1.0f));
        const float2 v9 = pfma(bc(m9),
            make_float2(__builtin_amdgcn_rcpf(e9.x), __builtin_amdgcn_rcpf(e9.y)),
            bc(o9));

        S1 = padd(S1, padd(padd(padd(v0, v1), padd(v2, v3)),
                           padd(padd(v4, v6), padd(padd(v7, v8), v9))));
        S2 = pfma(v0, v0, S2); S2 = pfma(v1, v1, S2); S2 = pfma(v2, v2, S2);
        S2 = pfma(v3, v3, S2); S2 = pfma(v4, v4, S2); S2 = pfma(v6, v6, S2);
        S2 = pfma(v7, v7, S2); S2 = pfma(v8, v8, S2); S2 = pfma(v9, v9, S2);

        float2 a = bc(accbase);
        a = pfma(bc(w[0]), v0, a); a = pfma(bc(w[1]), v1, a);
        a = pfma(bc(w[2]), v2, a); a = pfma(bc(w[3]), v3, a);
        a = pfma(bc(w[4]), v4, a); a = pfma(bc(w[6]), v6, a);
        a = pfma(bc(w[7]), v7, a); a = pfma(bc(w[8]), v8, a);
        a = pfma(bc(w[9]), v9, a);
        xn[p] = a;                 // in-place: xn[p] now holds acc
    }

    // c5 stats contribution (16 elements per lane)
    const float s1 = wave_sum_sgpr(S1.x + S1.y + 16.0f * v5);
    const float s2 = wave_sum_sgpr(fmaf(16.0f * v5, v5, S2.x + S2.y));

    constexpr float rn = 1.0f / (float)(C_DIM * D_DIM);
    const float mu2  = s1 * rn;
    const float var2 = s2 * rn - mu2 * mu2;
    const float rsig = rfl(rsqrtf(var2 + 1e-5f));

    // write output
    float* orow = out_weighted + (size_t)token * D_DIM + (lane << 2);
#pragma unroll
    for (int k = 0; k < 4; ++k) {
        const float2 lo = pmul(padd(xn[2 * k],     bc(-mu2)), bc(rsig));
        const float2 hi = pmul(padd(xn[2 * k + 1], bc(-mu2)), bc(rsig));
        float4 o;
        o.x = lo.x; o.y = lo.y; o.z = hi.x; o.w = hi.y;
        *reinterpret_cast<float4*>(orow + k * 256) = o;
    }
}

extern "C" void kernel_launch(void* const* d_in, const int* in_sizes, int n_in,
                              void* d_out, int out_size, void* d_ws, size_t ws_size,
                              hipStream_t stream) {
    const float* x   = (const float*)d_in[0];
    const float* lg  = (const float*)d_in[1];
    const float* lb  = (const float*)d_in[2];
    const float* lis = (const float*)d_in[3];
    const float* los = (const float*)d_in[4];
    const float* gw  = (const float*)d_in[5];
    const float* gb  = (const float*)d_in[6];

    const int tokens = in_sizes[0] / D_DIM;   // B*S = 8192
    float* out      = (float*)d_out;
    float* out_gate = out + (size_t)tokens * D_DIM;
    float* logits   = (float*)d_ws;           // tokens*16 floats = 512 KB

    const int tiles = (tokens + 15) / 16;
    hipLaunchKernelGGL(logits_kernel, dim3(tiles), dim3(64), 0, stream,
                       x, gw, gb, logits, tokens);

    const int g2 = (tokens + 3) / 4;
    hipLaunchKernelGGL(fused_kernel, dim3(g2), dim3(256), 0, stream,
                       x, lg, lb, lis, los, logits, out, out_gate, tokens);
}

// Round 15
// 28.473 us; speedup vs baseline: 1.4513x; 1.4513x over previous
//
#include <hip/hip_runtime.h>
#include <math.h>

// Problem constants (B=4, S=2048, D=1024, C=10)
constexpr int D_DIM = 1024;
constexpr int C_DIM = 10;
constexpr int WPB   = 8;            // waves (tokens) per block
constexpr int BLOCK = 64 * WPB;     // 512 threads

constexpr float CLAMP_V  = 1.0e6f;
constexpr float LOG2E    = 1.4426950408889634f;
constexpr float LN2      = 0.6931471805599453f;
constexpr float INV_2PI  = 0.15915494309189535f;

// native 2-wide float vector -> backend emits v_pk_{fma,mul,add}_f32 (VOP3P)
using v2 = __attribute__((ext_vector_type(2))) float;

__device__ __forceinline__ v2 mkv2(float a, float b) { v2 r; r.x = a; r.y = b; return r; }

// wave-uniform value -> SGPR
__device__ __forceinline__ float rfl(float x) {
    return __int_as_float(__builtin_amdgcn_readfirstlane(__float_as_int(x)));
}

// ---- DPP wave64 sum -> SGPR (full-rate VALU, no LDS pipe) ----
template <int CTRL>
__device__ __forceinline__ float dpp_add(float v) {
    const int s = __builtin_amdgcn_update_dpp(
        0, __float_as_int(v), CTRL, 0xf, 0xf, false);
    return v + __int_as_float(s);
}
__device__ __forceinline__ float wave_sum_sgpr(float v) {
    v = dpp_add<0x111>(v);   // row_shr:1
    v = dpp_add<0x112>(v);   // row_shr:2
    v = dpp_add<0x114>(v);   // row_shr:4
    v = dpp_add<0x118>(v);   // row_shr:8
    v = dpp_add<0x142>(v);   // row_bcast:15
    v = dpp_add<0x143>(v);   // row_bcast:31 -> lane 63 = total
    return __int_as_float(__builtin_amdgcn_readlane(__float_as_int(v), 63));
}

__global__ __launch_bounds__(BLOCK)   // natural allocation (forcing spills: r5/r7)
void fused_sme_kernel(const float* __restrict__ x,
                      const float* __restrict__ ln_gamma,
                      const float* __restrict__ ln_beta,
                      const float* __restrict__ log_in_scale,
                      const float* __restrict__ log_out_scale,
                      const float* __restrict__ gate_w,
                      const float* __restrict__ gate_b,
                      float* __restrict__ out_weighted,   // (tokens, D)
                      float* __restrict__ out_gate,       // (tokens, C)
                      int tokens)
{
    const int t    = threadIdx.x;
    const int lane = t & 63;
    const int wv   = t >> 6;
    const int token = blockIdx.x * WPB + wv;   // grid divides exactly (8192/8)

    __shared__ float gws[C_DIM * D_DIM];    // 40 KB: whole gate_w per block

    // ---- this wave's 16 x-elements as 8 v2 pairs: d = k*256 + lane*4 ----
    const float* xrow = x + (size_t)token * D_DIM + (lane << 2);
    v2 xp[8];
#pragma unroll
    for (int k = 0; k < 4; ++k) {
        const float4 f = *reinterpret_cast<const float4*>(xrow + k * 256);
        xp[2 * k]     = mkv2(f.x, f.y);
        xp[2 * k + 1] = mkv2(f.z, f.w);
    }

    // ---- cooperative gate_w stage: 2560 float4 over 512 threads ----
#pragma unroll
    for (int i = 0; i < 5; ++i) {
        const int idx = t + i * BLOCK;
        reinterpret_cast<float4*>(gws)[idx] =
            reinterpret_cast<const float4*>(gate_w)[idx];
    }

    // ---- LN partials (packed; overlap with staging latency) ----
    float r[12];
    {
        v2 s = {0.f, 0.f}, q = {0.f, 0.f};
#pragma unroll
        for (int p = 0; p < 8; ++p) {
            s += xp[p];
            q = xp[p] * xp[p] + q;
        }
        r[0] = wave_sum_sgpr(s.x + s.y);
        r[1] = wave_sum_sgpr(q.x + q.y);
    }

    __syncthreads();      // #1: gate_w resident in LDS

    // ---- gate dots from LDS (ds_read_b128; packed fma) ----
#pragma unroll
    for (int c = 0; c < C_DIM; ++c) {
        const float* gr = gws + c * D_DIM + (lane << 2);
        v2 d2 = {0.f, 0.f};
#pragma unroll
        for (int k = 0; k < 4; ++k) {
            const float4 g = *reinterpret_cast<const float4*>(gr + k * 256);
            d2 = xp[2 * k]     * mkv2(g.x, g.y) + d2;
            d2 = xp[2 * k + 1] * mkv2(g.z, g.w) + d2;
        }
        r[2 + c] = wave_sum_sgpr(d2.x + d2.y);
    }

    // ---- input LayerNorm stats (SGPR) ----
    const float mu   = r[0] * (1.0f / D_DIM);
    const float var  = r[1] * (1.0f / D_DIM) - mu * mu;
    const float rstd = rfl(rsqrtf(var + 1e-5f));

    // ---- gate softmax (wave-uniform) ----
    float w[C_DIM];
    float gmax = -3.4e38f;
#pragma unroll
    for (int c = 0; c < C_DIM; ++c) {
        w[c] = r[2 + c] + gate_b[c];
        gmax = fmaxf(gmax, w[c]);
    }
    float esum = 0.0f;
#pragma unroll
    for (int c = 0; c < C_DIM; ++c) {
        w[c] = __builtin_amdgcn_exp2f((w[c] - gmax) * LOG2E);
        esum += w[c];
    }
    const float rsum = __builtin_amdgcn_rcpf(esum);
#pragma unroll
    for (int c = 0; c < C_DIM; ++c) w[c] = rfl(w[c] * rsum);

    // gate output store early: overlaps with the candidate pass
    if (lane < C_DIM) out_gate[token * C_DIM + lane] = w[lane];

    // ---- scales (grid-uniform; one-time; SGPR via rfl) ----
    float in_s[C_DIM], out_s[C_DIM];
#pragma unroll
    for (int c = 0; c < C_DIM; ++c) {
        in_s[c]  = __builtin_amdgcn_exp2f(log_in_scale[c]  * LOG2E);
        out_s[c] = __builtin_amdgcn_exp2f(log_out_scale[c] * LOG2E);
    }
    // derived constants; |xn| <= ~42 => only exp's output clamp can fire
    const float a0 = rfl(out_s[0] * in_s[0]);
    const float a1 = rfl(out_s[1] * in_s[1] * in_s[1]);
    const float k2 = rfl(in_s[2]),           o2 = rfl(out_s[2]);
    const float k3 = rfl(in_s[3] * INV_2PI), o3 = rfl(out_s[3]);
    const float k4 = rfl(in_s[4] * LOG2E),   o4 = rfl(out_s[4]);
    const float v5 = rfl(fminf(out_s[5], CLAMP_V));
    const float a6 = rfl(out_s[6] * in_s[6] * in_s[6] * in_s[6]);
    const float k7 = rfl(in_s[7]),           o7 = rfl(out_s[7] * LN2);
    const float k8 = rfl(in_s[8]),           o8 = rfl(out_s[8]);
    const float k9 = rfl(2.0f * in_s[9] * LOG2E);
    const float o9 = rfl(out_s[9]),          m9 = rfl(-2.0f * out_s[9]);

    // ---- normalized x overwrites xp in place (packed) ----
#pragma unroll
    for (int k = 0; k < 4; ++k) {
        const float4 gv = *reinterpret_cast<const float4*>(ln_gamma + k * 256 + (lane << 2));
        const float4 bv = *reinterpret_cast<const float4*>(ln_beta  + k * 256 + (lane << 2));
        xp[2 * k]     = ((xp[2 * k]     - mu) * rstd) * mkv2(gv.x, gv.y) + mkv2(bv.x, bv.y);
        xp[2 * k + 1] = ((xp[2 * k + 1] - mu) * rstd) * mkv2(gv.z, gv.w) + mkv2(bv.z, bv.w);
    }

    // ---- candidate pass: joint-LN stats + gated accumulation (VOP3P packed,
    // SGPR constants). weighted = (sum_c w_c*cand_c - mu2)*rsig; post-LN
    // clip/nan dead; sum w = 1; c5 hoisted. acc overwrites xp in place. ----
    const float accbase = rfl(w[5] * v5);
    v2 S1 = {0.f, 0.f}, S2 = {0.f, 0.f};

#pragma unroll
    for (int p = 0; p < 8; ++p) {
        const v2 xj = xp[p];
        const v2 ax = mkv2(fabsf(xj.x), fabsf(xj.y));
        const v2 x2 = xj * xj;

        const v2 v0 = a0 * xj;
        const v2 v1 = a1 * x2;

        const v2 u2 = k2 * xj;
        const float c0 = __builtin_amdgcn_cosf(u2.x - rintf(u2.x));
        const float c1 = __builtin_amdgcn_cosf(u2.y - rintf(u2.y));
        const v2 vc2 = o2 * mkv2(c0, c1);

        const v2 u3 = k3 * xj;
        const float s0 = __builtin_amdgcn_sinf(u3.x - rintf(u3.x));
        const float s1v = __builtin_amdgcn_sinf(u3.y - rintf(u3.y));
        const v2 vc3 = o3 * mkv2(s0, s1v);

        const v2 u4 = k4 * xj;
        const v2 vc4 = mkv2(
            fminf(o4 * __builtin_amdgcn_exp2f(u4.x), CLAMP_V),
            fminf(o4 * __builtin_amdgcn_exp2f(u4.y), CLAMP_V));

        const v2 v6 = a6 * (x2 * xj);

        const v2 u7 = k7 * ax + 1.0f;
        const v2 vc7 = o7 * mkv2(__builtin_amdgcn_logf(u7.x),
                                 __builtin_amdgcn_logf(u7.y));

        const v2 u8 = k8 * ax;
        const v2 vc8 = o8 * mkv2(__builtin_amdgcn_sqrtf(u8.x),
                                 __builtin_amdgcn_sqrtf(u8.y));

        const v2 u9 = k9 * xj;
        const v2 vc9 = m9 * mkv2(
            __builtin_amdgcn_rcpf(__builtin_amdgcn_exp2f(u9.x) + 1.0f),
            __builtin_amdgcn_rcpf(__builtin_amdgcn_exp2f(u9.y) + 1.0f)) + o9;

        S1 += ((v0 + v1) + (vc2 + vc3)) + ((vc4 + v6) + (vc7 + vc8)) + vc9;
        S2 = v0 * v0 + S2;  S2 = v1 * v1 + S2;  S2 = vc2 * vc2 + S2;
        S2 = vc3 * vc3 + S2; S2 = vc4 * vc4 + S2; S2 = v6 * v6 + S2;
        S2 = vc7 * vc7 + S2; S2 = vc8 * vc8 + S2; S2 = vc9 * vc9 + S2;

        v2 a = mkv2(accbase, accbase);
        a = w[0] * v0 + a;  a = w[1] * v1 + a;  a = w[2] * vc2 + a;
        a = w[3] * vc3 + a; a = w[4] * vc4 + a; a = w[6] * v6 + a;
        a = w[7] * vc7 + a; a = w[8] * vc8 + a; a = w[9] * vc9 + a;
        xp[p] = a;                 // in-place: xp[p] now holds acc
    }

    // c5 stats contribution (16 elements per lane)
    const float s1 = wave_sum_sgpr(S1.x + S1.y + 16.0f * v5);
    const float s2 = wave_sum_sgpr(fmaf(16.0f * v5, v5, S2.x + S2.y));

    constexpr float rn = 1.0f / (float)(C_DIM * D_DIM);
    const float mu2  = s1 * rn;
    const float var2 = s2 * rn - mu2 * mu2;
    const float rsig = rfl(rsqrtf(var2 + 1e-5f));

    // ---- write outputs (packed epilogue) ----
    float* orow = out_weighted + (size_t)token * D_DIM + (lane << 2);
#pragma unroll
    for (int k = 0; k < 4; ++k) {
        const v2 lo = (xp[2 * k]     - mu2) * rsig;
        const v2 hi = (xp[2 * k + 1] - mu2) * rsig;
        float4 o;
        o.x = lo.x; o.y = lo.y; o.z = hi.x; o.w = hi.y;
        *reinterpret_cast<float4*>(orow + k * 256) = o;
    }
}

extern "C" void kernel_launch(void* const* d_in, const int* in_sizes, int n_in,
                              void* d_out, int out_size, void* d_ws, size_t ws_size,
                              hipStream_t stream) {
    const float* x   = (const float*)d_in[0];
    const float* lg  = (const float*)d_in[1];
    const float* lb  = (const float*)d_in[2];
    const float* lis = (const float*)d_in[3];
    const float* los = (const float*)d_in[4];
    const float* gw  = (const float*)d_in[5];
    const float* gb  = (const float*)d_in[6];

    const int tokens = in_sizes[0] / D_DIM;   // B*S = 8192
    float* out      = (float*)d_out;
    float* out_gate = out + (size_t)tokens * D_DIM;

    const int grid = (tokens + WPB - 1) / WPB;
    hipLaunchKernelGGL(fused_sme_kernel, dim3(grid), dim3(BLOCK), 0, stream,
                       x, lg, lb, lis, los, gw, gb, out, out_gate, tokens);
}